// Round 10
// baseline (848.810 us; speedup 1.0000x reference)
//
#include <hip/hip_runtime.h>
#include <hip/hip_fp16.h>
#include <math.h>

#define RSQRT32 0.17677669529663687f
#define NS 8          // dst slices (LDS hist/cursors: 6336*4 = 25 KB)
#define NC 32         // edge chunks per relation
#define MAXBS 6336    // max bins per slice (N=50000 -> BS=6250)
#define TILE 2048

typedef float fx2 __attribute__((ext_vector_type(2)));

// ---------------- CSR build: atomic-free counting sort ----------------

// Pass 1: per-(relation, slice, chunk) LDS histogram -> u16 partial counts.
__global__ void hist_lds(const int* __restrict__ e0, const int* __restrict__ e1,
                         const int* __restrict__ e2, int E, int N, int BS, int CH,
                         unsigned short* __restrict__ partial) {
    __shared__ unsigned int h[MAXBS];
    int blk = blockIdx.x;
    int c = blk % NC, s = (blk / NC) % NS, r = blk / (NC * NS);
    int lo = s * BS, hi = min(lo + BS, N), nb = hi - lo;
    for (int i = threadIdx.x; i < nb; i += 256) h[i] = 0;
    __syncthreads();
    const int* ei = (r == 0) ? e0 : ((r == 1) ? e1 : e2);
    int ebeg = c * CH, eend = min(ebeg + CH, E);
    const int* dst = ei + E;
    for (int i = ebeg + (int)threadIdx.x; i < eend; i += 256) {
        int d = dst[i];
        if (d >= lo && d < hi) atomicAdd(&h[d - lo], 1u);
    }
    __syncthreads();
    unsigned short* out = partial + ((size_t)blk) * BS;
    for (int i = threadIdx.x; i < nb; i += 256) out[i] = (unsigned short)h[i];
}

// Pass 2: per-bin exclusive scan over chunks (in place, u16) + totals -> cnt3.
__global__ void chunk_scan(unsigned short* __restrict__ partial, int* __restrict__ cnt3,
                           int N, int BS) {
    int t = blockIdx.x * blockDim.x + threadIdx.x;
    int tot = 3 * NS * BS;
    if (t >= tot) return;
    int r = t / (NS * BS);
    int rem = t - r * NS * BS;
    int s = rem / BS, bin = rem - s * BS;
    int d = s * BS + bin;
    if (d >= N) return;
    size_t base = ((size_t)(r * NS + s) * NC) * BS + bin;
    unsigned int run = 0;
    for (int c = 0; c < NC; ++c) {
        unsigned int v = partial[base + (size_t)c * BS];
        partial[base + (size_t)c * BS] = (unsigned short)run;
        run += v;
    }
    cnt3[(size_t)r * N + d] = (int)run;
}

// Coalesced two-level scan of cnt3 -> rp3 (row pointers).
__global__ void scan_tiles_sum(const int* __restrict__ cnt3, int* __restrict__ tsum,
                               int N, int G) {
    int blk = blockIdx.x, r = blk / G, g = blk - r * G;
    int base = g * TILE;
    const int* cnt = cnt3 + (size_t)r * N;
    int s = 0;
    for (int i = threadIdx.x; i < TILE; i += 256) {
        int idx = base + i;
        s += (idx < N) ? cnt[idx] : 0;
    }
    __shared__ int wsum[4];
    for (int m = 32; m; m >>= 1) s += __shfl_down(s, m);
    if ((threadIdx.x & 63) == 0) wsum[threadIdx.x >> 6] = s;
    __syncthreads();
    if (threadIdx.x == 0) tsum[blk] = wsum[0] + wsum[1] + wsum[2] + wsum[3];
}

__global__ void scan_offsets(int* __restrict__ tsum, int* __restrict__ rp3, int N, int G) {
    int r = threadIdx.x;
    if (r < 3) {
        int run = 0;
        for (int g = 0; g < G; ++g) { int v = tsum[r * G + g]; tsum[r * G + g] = run; run += v; }
        rp3[(size_t)r * (N + 1) + N] = run;
    }
}

__global__ void scan_write(const int* __restrict__ cnt3, const int* __restrict__ toff,
                           int* __restrict__ rp3, int N, int G) {
    int blk = blockIdx.x, r = blk / G, g = blk - r * G;
    int base = g * TILE;
    const int* cnt = cnt3 + (size_t)r * N;
    int* rp = rp3 + (size_t)r * (N + 1);
    __shared__ int part[256];
    int t = threadIdx.x;
    int v[8]; int s = 0;
    #pragma unroll
    for (int j = 0; j < 8; ++j) {
        int idx = base + t * 8 + j;
        int x = (idx < N) ? cnt[idx] : 0;
        v[j] = s; s += x;
    }
    part[t] = s;
    __syncthreads();
    for (int off = 1; off < 256; off <<= 1) {
        int x = (t >= off) ? part[t - off] : 0;
        __syncthreads();
        part[t] += x;
        __syncthreads();
    }
    int texcl = part[t] - s + toff[blk];
    #pragma unroll
    for (int j = 0; j < 8; ++j) {
        int idx = base + t * 8 + j;
        if (idx < N) rp[idx] = texcl + v[j];
    }
}

// Pass 3: scatter via LDS cursors; no global atomics.
// XCD-aligned (NS=8): slice = blk&7 so all chunk-blocks of one slice run on one
// XCD -> partial-line writes to the slice's adj region merge in that XCD's L2.
__global__ void scatter_cs(const int* __restrict__ e0, const int* __restrict__ e1,
                           const int* __restrict__ e2, const float* __restrict__ ea,
                           const unsigned short* __restrict__ partial,
                           const int* __restrict__ rp3,
                           int2* __restrict__ adj0, int* __restrict__ adj12,
                           int E, int N, int BS, int CH) {
    __shared__ unsigned int cur[MAXBS];
    int blk = blockIdx.x;
    int s = blk & 7;
    int rest = blk >> 3;
    int c = rest % NC, r = rest / NC;
    int pblk = c + NC * (s + NS * r);     // partial-buffer index (hist layout)
    int lo = s * BS, hi = min(lo + BS, N), nb = hi - lo;
    const unsigned short* po = partial + ((size_t)pblk) * BS;
    const int* rp = rp3 + (size_t)r * (N + 1);
    for (int i = threadIdx.x; i < nb; i += 256)
        cur[i] = (unsigned int)rp[lo + i] + (unsigned int)po[i];
    __syncthreads();
    const int* ei = (r == 0) ? e0 : ((r == 1) ? e1 : e2);
    const int* srcp = ei;
    const int* dstp = ei + E;
    int ebeg = c * CH, eend = min(ebeg + CH, E);
    if (r == 0) {
        for (int i = ebeg + (int)threadIdx.x; i < eend; i += 256) {
            int d = dstp[i];
            if (d < lo || d >= hi) continue;
            unsigned int pos = atomicAdd(&cur[d - lo], 1u);
            int2 v; v.x = srcp[i]; v.y = __float_as_int(ea[i]);
            adj0[pos] = v;
        }
    } else {
        int* adj = adj12 + (size_t)(r - 1) * E;
        for (int i = ebeg + (int)threadIdx.x; i < eend; i += 256) {
            int d = dstp[i];
            if (d < lo || d >= hi) continue;
            unsigned int pos = atomicAdd(&cur[d - lo], 1u);
            adj[pos] = srcp[i];
        }
    }
}

// ---------------- misc small kernels ----------------

// colsum of We -> u[3][32]; also zero-inits bstart/bend (runs before bounds_kernel).
__global__ void colsum_kernel(const float* __restrict__ We, float* __restrict__ u,
                              int* __restrict__ bstart, int* __restrict__ bend, int B) {
    int t = threadIdx.x;
    if (t < 96) {
        int w = t >> 5, j = t & 31;
        const float* W = We + w * 1024;
        float s = 0.f;
        #pragma unroll
        for (int kk = 0; kk < 32; ++kk) s += W[kk * 32 + j];
        u[t] = s;
    }
    if (t < B) { bstart[t] = 0; bend[t] = 0; }
}

// batch is sorted: graph bounds are run boundaries -> plain unique stores.
__global__ void bounds_kernel(const int* __restrict__ batch, int* __restrict__ bstart,
                              int* __restrict__ bend, int N) {
    int t = blockIdx.x * blockDim.x + threadIdx.x;
    if (t >= N) return;
    int b = batch[t];
    if (t == 0 || batch[t - 1] != b) bstart[b] = t;
    if (t == N - 1 || batch[t + 1] != b) bend[b] = t + 1;
}

// ---------------- per-layer: fused q,k,v,skip GEMMs (+qdotu) ----------------
// lanes 0-31: q (xd) & v (xs) columns; lanes 32-63: k (xs) & skip (xd) columns.
// kv packed fp8 e4m3 (HW cvt, self-consistent encode/decode):
// row = 8 x uint2; quad cq at offset cq: {4 k-bytes, 4 v-bytes} -> 64B/node.
__global__ void qkvs_kernel(
    const float* __restrict__ xs, int ssrc,
    const float* __restrict__ xd, int sdst,
    const float* __restrict__ Wq, const float* __restrict__ bq,
    const float* __restrict__ Wk, const float* __restrict__ bk,
    const float* __restrict__ Wv, const float* __restrict__ bv,
    const float* __restrict__ Ws, const float* __restrict__ bs,
    const float* __restrict__ u,      // nullptr for non-edge layers
    float* __restrict__ qb, uint2* __restrict__ kv8,
    float* __restrict__ sb, float* __restrict__ qdu, int N)
{
    int lane = threadIdx.x & 63;
    int wid  = __builtin_amdgcn_readfirstlane((int)(threadIdx.x >> 6));
    int wpb  = blockDim.x >> 6;
    int gw   = blockIdx.x * wpb + wid;
    int nw   = gridDim.x * wpb;
    int j    = lane & 31;
    bool lower = lane < 32;

    const float* W1 = lower ? Wq : Wk;
    const float* W2 = lower ? Wv : Ws;
    float rw1[32], rw2[32];
    #pragma unroll
    for (int kk = 0; kk < 32; ++kk) {
        rw1[kk] = W1[kk * 32 + j];
        rw2[kk] = W2[kk * 32 + j];
    }
    float bias1 = lower ? bq[j] : bk[j];
    float bias2 = lower ? bv[j] : bs[j];
    float uj = (u != nullptr) ? u[j] : 0.f;

    for (int n = gw; n < N; n += nw) {
        const float* xdr = xd + (size_t)n * sdst;  // wave-uniform -> scalar loads
        const float* xsr = xs + (size_t)n * ssrc;
        float acc1 = bias1, acc2 = bias2;
        #pragma unroll
        for (int kk = 0; kk < 32; ++kk) {
            float xdv = xdr[kk];
            float xsv = xsr[kk];
            float a  = lower ? xdv : xsv;   // q | k input
            float bb = lower ? xsv : xdv;   // v | skip input
            acc1 = fmaf(a,  rw1[kk], acc1);
            acc2 = fmaf(bb, rw2[kk], acc2);
        }
        float kk_ = __shfl(acc1, j + 32);   // k_j from upper half
        // collect quad (k,v) values; only quad leaders (j%4==0) pack+store
        float k1 = __shfl_down(kk_, 1), v1 = __shfl_down(acc2, 1);
        float k2 = __shfl_down(kk_, 2), v2 = __shfl_down(acc2, 2);
        float k3 = __shfl_down(kk_, 3), v3 = __shfl_down(acc2, 3);
        if (lower) {
            qb[(size_t)n * 32 + j] = acc1;                  // q
            if ((j & 3) == 0) {
                int pk = __builtin_amdgcn_cvt_pk_fp8_f32(kk_, k1, 0, false);
                pk = __builtin_amdgcn_cvt_pk_fp8_f32(k2, k3, pk, true);
                int pv = __builtin_amdgcn_cvt_pk_fp8_f32(acc2, v1, 0, false);
                pv = __builtin_amdgcn_cvt_pk_fp8_f32(v2, v3, pv, true);
                kv8[(size_t)n * 8 + (j >> 2)] = make_uint2((unsigned)pk, (unsigned)pv);
            }
        } else {
            sb[(size_t)n * 32 + j] = acc2;                  // skip
        }
        if (u != nullptr) {
            float pp = lower ? acc1 * uj : 0.f;
            pp += __shfl_xor(pp, 16);
            pp += __shfl_xor(pp, 8);
            pp += __shfl_xor(pp, 4);
            pp += __shfl_xor(pp, 2);
            pp += __shfl_xor(pp, 1);
            if (lane == 0) qdu[n] = pp * RSQRT32;
        }
    }
}

// ---------------- per-layer: gather aggregation + fused mean-pool -------------
// One wave per dst node. Octet layout: 8 lanes/edge, lane cq owns channels
// 4cq..4cq+3 (uint2 fp8 = 64B coalesced row read). 8 streams x 2-way ILP.
// Epilogue: tanh + xout store + cross-wave LDS pool reduce (32 atomics/block).
template<int HAS_EA>
__global__ __launch_bounds__(256, 8)
void agg_kernel(const int* __restrict__ rp, const void* __restrict__ adjv,
    const float* __restrict__ qb, const uint2* __restrict__ kv8,
    const float* __restrict__ qdu, const float* __restrict__ u,
    const float* __restrict__ skp, float* __restrict__ xout,
    const int* __restrict__ batch, float* __restrict__ poolsum,
    int layer_off, int N)
{
    __shared__ float4 red4[32];
    int t = threadIdx.x;
    int w = t >> 6, lane = t & 63;
    int cq = lane & 7;        // channel quad
    int o  = lane >> 3;       // octet (edge stream)
    int n = blockIdx.x * 4 + w;
    bool valid = (n < N);
    float4 ov = make_float4(0.f, 0.f, 0.f, 0.f);
    if (valid) {
        float4 qc = ((const float4*)(qb + (size_t)n * 32))[cq];
        float qd = HAS_EA ? qdu[n] : 0.f;
        float4 uc = HAS_EA ? ((const float4*)u)[cq] : make_float4(0.f, 0.f, 0.f, 0.f);
        int beg = rp[n], end = rp[n + 1];
        float den0 = 0.f, den1 = 0.f;
        float4 num0 = make_float4(0.f, 0.f, 0.f, 0.f);
        float4 num1 = make_float4(0.f, 0.f, 0.f, 0.f);
        const int2* adjE = (const int2*)adjv;
        const int*  adjP = (const int*)adjv;
        int i = beg + o;
        for (; i + 8 < end; i += 16) {
            int s0, s1; float ae0 = 0.f, ae1 = 0.f;
            if (HAS_EA) {
                int2 a0 = adjE[i], a1 = adjE[i + 8];
                s0 = a0.x; s1 = a1.x;
                ae0 = __int_as_float(a0.y); ae1 = __int_as_float(a1.y);
            } else { s0 = adjP[i]; s1 = adjP[i + 8]; }
            uint2 p0 = kv8[(size_t)s0 * 8 + cq];
            uint2 p1 = kv8[(size_t)s1 * 8 + cq];
            fx2 k001 = __builtin_amdgcn_cvt_pk_f32_fp8((int)p0.x, false);
            fx2 k023 = __builtin_amdgcn_cvt_pk_f32_fp8((int)p0.x, true);
            fx2 w001 = __builtin_amdgcn_cvt_pk_f32_fp8((int)p0.y, false);
            fx2 w023 = __builtin_amdgcn_cvt_pk_f32_fp8((int)p0.y, true);
            fx2 k101 = __builtin_amdgcn_cvt_pk_f32_fp8((int)p1.x, false);
            fx2 k123 = __builtin_amdgcn_cvt_pk_f32_fp8((int)p1.x, true);
            fx2 w101 = __builtin_amdgcn_cvt_pk_f32_fp8((int)p1.y, false);
            fx2 w123 = __builtin_amdgcn_cvt_pk_f32_fp8((int)p1.y, true);
            float d0 = fmaf(qc.x, k001[0], fmaf(qc.y, k001[1], fmaf(qc.z, k023[0], qc.w * k023[1])));
            float d1 = fmaf(qc.x, k101[0], fmaf(qc.y, k101[1], fmaf(qc.z, k123[0], qc.w * k123[1])));
            d0 += __shfl_xor(d0, 4);  d1 += __shfl_xor(d1, 4);
            d0 += __shfl_xor(d0, 2);  d1 += __shfl_xor(d1, 2);
            d0 += __shfl_xor(d0, 1);  d1 += __shfl_xor(d1, 1);
            // softmax is shift-invariant; logits O(+-7) so direct exp is safe
            float ex0 = __expf(fmaf(ae0, qd, d0 * RSQRT32));
            float ex1 = __expf(fmaf(ae1, qd, d1 * RSQRT32));
            den0 += ex0;  den1 += ex1;
            num0.x = fmaf(fmaf(ae0, uc.x, w001[0]), ex0, num0.x);
            num0.y = fmaf(fmaf(ae0, uc.y, w001[1]), ex0, num0.y);
            num0.z = fmaf(fmaf(ae0, uc.z, w023[0]), ex0, num0.z);
            num0.w = fmaf(fmaf(ae0, uc.w, w023[1]), ex0, num0.w);
            num1.x = fmaf(fmaf(ae1, uc.x, w101[0]), ex1, num1.x);
            num1.y = fmaf(fmaf(ae1, uc.y, w101[1]), ex1, num1.y);
            num1.z = fmaf(fmaf(ae1, uc.z, w123[0]), ex1, num1.z);
            num1.w = fmaf(fmaf(ae1, uc.w, w123[1]), ex1, num1.w);
        }
        for (; i < end; i += 8) {
            int s0; float ae0 = 0.f;
            if (HAS_EA) { int2 a0 = adjE[i]; s0 = a0.x; ae0 = __int_as_float(a0.y); }
            else s0 = adjP[i];
            uint2 p0 = kv8[(size_t)s0 * 8 + cq];
            fx2 k001 = __builtin_amdgcn_cvt_pk_f32_fp8((int)p0.x, false);
            fx2 k023 = __builtin_amdgcn_cvt_pk_f32_fp8((int)p0.x, true);
            fx2 w001 = __builtin_amdgcn_cvt_pk_f32_fp8((int)p0.y, false);
            fx2 w023 = __builtin_amdgcn_cvt_pk_f32_fp8((int)p0.y, true);
            float d0 = fmaf(qc.x, k001[0], fmaf(qc.y, k001[1], fmaf(qc.z, k023[0], qc.w * k023[1])));
            d0 += __shfl_xor(d0, 4);
            d0 += __shfl_xor(d0, 2);
            d0 += __shfl_xor(d0, 1);
            float ex0 = __expf(fmaf(ae0, qd, d0 * RSQRT32));
            den0 += ex0;
            num0.x = fmaf(fmaf(ae0, uc.x, w001[0]), ex0, num0.x);
            num0.y = fmaf(fmaf(ae0, uc.y, w001[1]), ex0, num0.y);
            num0.z = fmaf(fmaf(ae0, uc.z, w023[0]), ex0, num0.z);
            num0.w = fmaf(fmaf(ae0, uc.w, w023[1]), ex0, num0.w);
        }
        float den = den0 + den1;
        float4 num = make_float4(num0.x + num1.x, num0.y + num1.y,
                                 num0.z + num1.z, num0.w + num1.w);
        den   += __shfl_xor(den, 8);   den   += __shfl_xor(den, 16);   den   += __shfl_xor(den, 32);
        num.x += __shfl_xor(num.x, 8); num.x += __shfl_xor(num.x, 16); num.x += __shfl_xor(num.x, 32);
        num.y += __shfl_xor(num.y, 8); num.y += __shfl_xor(num.y, 16); num.y += __shfl_xor(num.y, 32);
        num.z += __shfl_xor(num.z, 8); num.z += __shfl_xor(num.z, 16); num.z += __shfl_xor(num.z, 32);
        num.w += __shfl_xor(num.w, 8); num.w += __shfl_xor(num.w, 16); num.w += __shfl_xor(num.w, 32);
        if (o == 0) {
            float inv = 1.f / (den + 1e-16f);
            float4 sk = ((const float4*)(skp + (size_t)n * 32))[cq];
            ov.x = tanhf(fmaf(num.x, inv, sk.x));
            ov.y = tanhf(fmaf(num.y, inv, sk.y));
            ov.z = tanhf(fmaf(num.z, inv, sk.z));
            ov.w = tanhf(fmaf(num.w, inv, sk.w));
            ((float4*)(xout + (size_t)n * 32))[cq] = ov;
        }
    }
    // ---- fused mean-pool accumulation (batch sorted: blocks usually uniform) ----
    int n0 = blockIdx.x * 4;
    int nlast = min(n0 + 3, N - 1);
    bool uniform = (batch[n0] == batch[nlast]);
    if (o == 0) red4[w * 8 + cq] = ov;
    __syncthreads();
    if (uniform) {
        if (t < 8) {
            float4 s0 = red4[t], s1 = red4[t + 8], s2 = red4[t + 16], s3 = red4[t + 24];
            float* dst = poolsum + (size_t)batch[n0] * 288 + layer_off + 4 * t;
            atomicAdd(&dst[0], s0.x + s1.x + s2.x + s3.x);
            atomicAdd(&dst[1], s0.y + s1.y + s2.y + s3.y);
            atomicAdd(&dst[2], s0.z + s1.z + s2.z + s3.z);
            atomicAdd(&dst[3], s0.w + s1.w + s2.w + s3.w);
        }
    } else if (valid && o == 0) {
        float* dst = poolsum + (size_t)batch[n] * 288 + layer_off + 4 * cq;
        atomicAdd(&dst[0], ov.x);
        atomicAdd(&dst[1], ov.y);
        atomicAdd(&dst[2], ov.z);
        atomicAdd(&dst[3], ov.w);
    }
}

// ---------------- head ----------------

__device__ __forceinline__ void gemv_step(const float* __restrict__ W, const float* __restrict__ bias,
    const float* sin_, float* sout, int K, int M, int t, bool do_relu) {
    if (t < M) {
        float acc = bias[t];
        for (int kk = 0; kk < K; ++kk) acc = fmaf(sin_[kk], W[kk * M + t], acc);
        sout[t] = do_relu ? fmaxf(acc, 0.f) : acc;
    }
    __syncthreads();
}

// One block per graph. (mean-pool commutes with W1: mean(s@W1+b1) = mean(s)@W1+b1)
__global__ void head_kernel(const float* __restrict__ poolsum,
    const int* __restrict__ bstart, const int* __restrict__ bend,
    const float* __restrict__ W1, const float* __restrict__ b1,
    const float* __restrict__ W2, const float* __restrict__ b2,
    const float* __restrict__ W3, const float* __restrict__ b3,
    const float* __restrict__ W4, const float* __restrict__ b4,
    const float* __restrict__ W5, const float* __restrict__ b5,
    const float* __restrict__ W6, const float* __restrict__ b6,
    float* __restrict__ out)
{
    __shared__ float ha[288], hb[288];
    __shared__ float lse;
    int b = blockIdx.x, t = threadIdx.x;
    float invc = 1.f / fmaxf((float)(bend[b] - bstart[b]), 1.f);
    if (t < 288) ha[t] = poolsum[(size_t)b * 288 + t] * invc;
    __syncthreads();
    gemv_step(W1, b1, ha, hb, 288, 288, t, false);
    gemv_step(W2, b2, hb, ha, 288, 144, t, true);
    gemv_step(W3, b3, ha, hb, 144, 144, t, false);
    gemv_step(W4, b4, hb, ha, 144, 72,  t, false);
    gemv_step(W5, b5, ha, hb, 72,  72,  t, false);
    gemv_step(W6, b6, hb, ha, 72,  10,  t, false);
    if (t == 0) {
        float m = ha[0];
        for (int i = 1; i < 10; ++i) m = fmaxf(m, ha[i]);
        float ssum = 0.f;
        for (int i = 0; i < 10; ++i) ssum += __expf(ha[i] - m);
        lse = m + logf(ssum);
    }
    __syncthreads();
    if (t < 10) out[b * 10 + t] = ha[t] - lse;
}

// ---------------- launch ----------------

extern "C" void kernel_launch(void* const* d_in, const int* in_sizes, int n_in,
                              void* d_out, int out_size, void* d_ws, size_t ws_size,
                              hipStream_t stream)
{
    const float* inter_emb = (const float*)d_in[0];
    const float* edge_attr = (const float*)d_in[1];
    const float* uv_emb    = (const float*)d_in[2];
    const int* inter_idx = (const int*)d_in[3];
    const int* uvt_idx   = (const int*)d_in[4];
    const int* tuv_idx   = (const int*)d_in[5];
    const int* batch     = (const int*)d_in[6];
    const float* cWq = (const float*)d_in[7];  const float* cbq = (const float*)d_in[8];
    const float* cWk = (const float*)d_in[9];  const float* cbk = (const float*)d_in[10];
    const float* cWv = (const float*)d_in[11]; const float* cbv = (const float*)d_in[12];
    const float* cWs = (const float*)d_in[13]; const float* cbs = (const float*)d_in[14];
    const float* cWe = (const float*)d_in[15];
    const float* W1 = (const float*)d_in[16]; const float* b1 = (const float*)d_in[17];
    const float* W2 = (const float*)d_in[18]; const float* b2 = (const float*)d_in[19];
    const float* W3 = (const float*)d_in[20]; const float* b3 = (const float*)d_in[21];
    const float* W4 = (const float*)d_in[22]; const float* b4 = (const float*)d_in[23];
    const float* W5 = (const float*)d_in[24]; const float* b5 = (const float*)d_in[25];
    const float* W6 = (const float*)d_in[26]; const float* b6 = (const float*)d_in[27];

    const int N = in_sizes[2] / 32;
    const int E = in_sizes[1];
    const int B = out_size / 10;
    const int G = (N + TILE - 1) / TILE;
    const int BS = (N + NS - 1) / NS;      // bins per slice (<= MAXBS)
    const int CH = (E + NC - 1) / NC;      // edges per chunk

    char* p = (char*)d_ws;
    auto alloc = [&](size_t bytes) { char* r = p; p += (bytes + 255) & ~(size_t)255; return r; };
    float*   qb    = (float*)alloc((size_t)N * 32 * 4);
    uint2*   kv8   = (uint2*)alloc((size_t)N * 64);     // fp8 {k[4],v[4]} per quad
    float*   sb    = (float*)alloc((size_t)N * 32 * 4);
    float*   qdu   = (float*)alloc((size_t)N * 4);
    float*   xa    = (float*)alloc((size_t)N * 32 * 4);
    float*   xb    = (float*)alloc((size_t)N * 32 * 4);
    float*   ub    = (float*)alloc(96 * 4);
    float*   poolsum = (float*)alloc((size_t)B * 288 * 4);
    int*     bstart = (int*)alloc((size_t)B * 4);
    int*     bend   = (int*)alloc((size_t)B * 4);
    int*     cnt3  = (int*)alloc((size_t)3 * N * 4);
    int*     rp3   = (int*)alloc((size_t)3 * (N + 1) * 4);
    int*     tsum  = (int*)alloc((size_t)3 * G * 4);
    unsigned short* partial = (unsigned short*)alloc((size_t)3 * NS * NC * BS * 2);
    int2*    adj0  = (int2*)alloc((size_t)E * 8);
    int*     adj12 = (int*)alloc((size_t)2 * E * 4);

    // ---- CSR build: counting sort, no global atomics ----
    hist_lds<<<3 * NS * NC, 256, 0, stream>>>(inter_idx, uvt_idx, tuv_idx, E, N, BS, CH, partial);
    chunk_scan<<<(3 * NS * BS + 255) / 256, 256, 0, stream>>>(partial, cnt3, N, BS);
    scan_tiles_sum<<<3 * G, 256, 0, stream>>>(cnt3, tsum, N, G);
    scan_offsets<<<1, 64, 0, stream>>>(tsum, rp3, N, G);
    scan_write<<<3 * G, 256, 0, stream>>>(cnt3, tsum, rp3, N, G);
    scatter_cs<<<3 * NS * NC, 256, 0, stream>>>(inter_idx, uvt_idx, tuv_idx, edge_attr,
                                                partial, rp3, adj0, adj12, E, N, BS, CH);

    hipMemsetAsync(poolsum, 0, (size_t)B * 288 * 4, stream);
    colsum_kernel<<<1, 128, 0, stream>>>(cWe, ub, bstart, bend, B);
    bounds_kernel<<<(N + 255) / 256, 256, 0, stream>>>(batch, bstart, bend, N);

    float* xcur = nullptr;
    float* xnext = xa;
    for (int i = 0; i < 9; ++i) {
        int r = i % 3;
        const float* xsrc; int ssrc; const float* xdst; int sdst;
        if (i == 0)      { xsrc = inter_emb; ssrc = 64; xdst = inter_emb + 32; sdst = 64; }
        else if (r == 0) { xsrc = xcur; ssrc = 32; xdst = xcur;  sdst = 32; }
        else if (r == 1) { xsrc = xcur; ssrc = 32; xdst = uv_emb; sdst = 32; }
        else             { xsrc = uv_emb; ssrc = 32; xdst = xcur; sdst = 32; }
        const float* ul = (r == 0) ? (ub + (i / 3) * 32) : nullptr;

        qkvs_kernel<<<1024, 256, 0, stream>>>(xsrc, ssrc, xdst, sdst,
            cWq + i * 1024, cbq + i * 32, cWk + i * 1024, cbk + i * 32,
            cWv + i * 1024, cbv + i * 32, cWs + i * 1024, cbs + i * 32,
            ul, qb, kv8, sb, qdu, N);
        const int* rpl = rp3 + (size_t)r * (N + 1);
        if (r == 0) {
            agg_kernel<1><<<(N + 3) / 4, 256, 0, stream>>>(
                rpl, adj0, qb, kv8, qdu, ul, sb, xnext, batch, poolsum, i * 32, N);
        } else {
            agg_kernel<0><<<(N + 3) / 4, 256, 0, stream>>>(
                rpl, adj12 + (size_t)(r - 1) * E, qb, kv8, qdu, ul, sb, xnext,
                batch, poolsum, i * 32, N);
        }
        xcur = xnext;
        xnext = (xnext == xa) ? xb : xa;
    }

    head_kernel<<<B, 320, 0, stream>>>(poolsum, bstart, bend,
        W1, b1, W2, b2, W3, b3, W4, b4, W5, b5, W6, b6, (float*)d_out);
}

// Round 11
// 537.871 us; speedup vs baseline: 1.5781x; 1.5781x over previous
//
#include <hip/hip_runtime.h>
#include <hip/hip_fp16.h>
#include <math.h>

#define RSQRT32 0.17677669529663687f
#define NS 8          // dst slices (LDS hist/cursors: 6336*4 = 25 KB)
#define NC 32         // edge chunks per relation
#define MAXBS 6336    // max bins per slice (N=50000 -> BS=6250)
#define TILE 2048

typedef float fx2 __attribute__((ext_vector_type(2)));

// ---------------- CSR build: atomic-free counting sort ----------------

__global__ void hist_lds(const int* __restrict__ e0, const int* __restrict__ e1,
                         const int* __restrict__ e2, int E, int N, int BS, int CH,
                         unsigned short* __restrict__ partial) {
    __shared__ unsigned int h[MAXBS];
    int blk = blockIdx.x;
    int c = blk % NC, s = (blk / NC) % NS, r = blk / (NC * NS);
    int lo = s * BS, hi = min(lo + BS, N), nb = hi - lo;
    for (int i = threadIdx.x; i < nb; i += 256) h[i] = 0;
    __syncthreads();
    const int* ei = (r == 0) ? e0 : ((r == 1) ? e1 : e2);
    int ebeg = c * CH, eend = min(ebeg + CH, E);
    const int* dst = ei + E;
    for (int i = ebeg + (int)threadIdx.x; i < eend; i += 256) {
        int d = dst[i];
        if (d >= lo && d < hi) atomicAdd(&h[d - lo], 1u);
    }
    __syncthreads();
    unsigned short* out = partial + ((size_t)blk) * BS;
    for (int i = threadIdx.x; i < nb; i += 256) out[i] = (unsigned short)h[i];
}

__global__ void chunk_scan(unsigned short* __restrict__ partial, int* __restrict__ cnt3,
                           int N, int BS) {
    int t = blockIdx.x * blockDim.x + threadIdx.x;
    int tot = 3 * NS * BS;
    if (t >= tot) return;
    int r = t / (NS * BS);
    int rem = t - r * NS * BS;
    int s = rem / BS, bin = rem - s * BS;
    int d = s * BS + bin;
    if (d >= N) return;
    size_t base = ((size_t)(r * NS + s) * NC) * BS + bin;
    unsigned int run = 0;
    for (int c = 0; c < NC; ++c) {
        unsigned int v = partial[base + (size_t)c * BS];
        partial[base + (size_t)c * BS] = (unsigned short)run;
        run += v;
    }
    cnt3[(size_t)r * N + d] = (int)run;
}

__global__ void scan_tiles_sum(const int* __restrict__ cnt3, int* __restrict__ tsum,
                               int N, int G) {
    int blk = blockIdx.x, r = blk / G, g = blk - r * G;
    int base = g * TILE;
    const int* cnt = cnt3 + (size_t)r * N;
    int s = 0;
    for (int i = threadIdx.x; i < TILE; i += 256) {
        int idx = base + i;
        s += (idx < N) ? cnt[idx] : 0;
    }
    __shared__ int wsum[4];
    for (int m = 32; m; m >>= 1) s += __shfl_down(s, m);
    if ((threadIdx.x & 63) == 0) wsum[threadIdx.x >> 6] = s;
    __syncthreads();
    if (threadIdx.x == 0) tsum[blk] = wsum[0] + wsum[1] + wsum[2] + wsum[3];
}

__global__ void scan_offsets(int* __restrict__ tsum, int* __restrict__ rp3, int N, int G) {
    int r = threadIdx.x;
    if (r < 3) {
        int run = 0;
        for (int g = 0; g < G; ++g) { int v = tsum[r * G + g]; tsum[r * G + g] = run; run += v; }
        rp3[(size_t)r * (N + 1) + N] = run;
    }
}

__global__ void scan_write(const int* __restrict__ cnt3, const int* __restrict__ toff,
                           int* __restrict__ rp3, int N, int G) {
    int blk = blockIdx.x, r = blk / G, g = blk - r * G;
    int base = g * TILE;
    const int* cnt = cnt3 + (size_t)r * N;
    int* rp = rp3 + (size_t)r * (N + 1);
    __shared__ int part[256];
    int t = threadIdx.x;
    int v[8]; int s = 0;
    #pragma unroll
    for (int j = 0; j < 8; ++j) {
        int idx = base + t * 8 + j;
        int x = (idx < N) ? cnt[idx] : 0;
        v[j] = s; s += x;
    }
    part[t] = s;
    __syncthreads();
    for (int off = 1; off < 256; off <<= 1) {
        int x = (t >= off) ? part[t - off] : 0;
        __syncthreads();
        part[t] += x;
        __syncthreads();
    }
    int texcl = part[t] - s + toff[blk];
    #pragma unroll
    for (int j = 0; j < 8; ++j) {
        int idx = base + t * 8 + j;
        if (idx < N) rp[idx] = texcl + v[j];
    }
}

// Pass 3: scatter via LDS cursors; XCD-aligned slices (slice = blk&7).
__global__ void scatter_cs(const int* __restrict__ e0, const int* __restrict__ e1,
                           const int* __restrict__ e2, const float* __restrict__ ea,
                           const unsigned short* __restrict__ partial,
                           const int* __restrict__ rp3,
                           int2* __restrict__ adj0, int* __restrict__ adj12,
                           int E, int N, int BS, int CH) {
    __shared__ unsigned int cur[MAXBS];
    int blk = blockIdx.x;
    int s = blk & 7;
    int rest = blk >> 3;
    int c = rest % NC, r = rest / NC;
    int pblk = c + NC * (s + NS * r);
    int lo = s * BS, hi = min(lo + BS, N), nb = hi - lo;
    const unsigned short* po = partial + ((size_t)pblk) * BS;
    const int* rp = rp3 + (size_t)r * (N + 1);
    for (int i = threadIdx.x; i < nb; i += 256)
        cur[i] = (unsigned int)rp[lo + i] + (unsigned int)po[i];
    __syncthreads();
    const int* ei = (r == 0) ? e0 : ((r == 1) ? e1 : e2);
    const int* srcp = ei;
    const int* dstp = ei + E;
    int ebeg = c * CH, eend = min(ebeg + CH, E);
    if (r == 0) {
        for (int i = ebeg + (int)threadIdx.x; i < eend; i += 256) {
            int d = dstp[i];
            if (d < lo || d >= hi) continue;
            unsigned int pos = atomicAdd(&cur[d - lo], 1u);
            int2 v; v.x = srcp[i]; v.y = __float_as_int(ea[i]);
            adj0[pos] = v;
        }
    } else {
        int* adj = adj12 + (size_t)(r - 1) * E;
        for (int i = ebeg + (int)threadIdx.x; i < eend; i += 256) {
            int d = dstp[i];
            if (d < lo || d >= hi) continue;
            unsigned int pos = atomicAdd(&cur[d - lo], 1u);
            adj[pos] = srcp[i];
        }
    }
}

// ---------------- misc small kernels ----------------

__global__ void colsum_kernel(const float* __restrict__ We, float* __restrict__ u,
                              int* __restrict__ bstart, int* __restrict__ bend, int B) {
    int t = threadIdx.x;
    if (t < 96) {
        int w = t >> 5, j = t & 31;
        const float* W = We + w * 1024;
        float s = 0.f;
        #pragma unroll
        for (int kk = 0; kk < 32; ++kk) s += W[kk * 32 + j];
        u[t] = s;
    }
    if (t < B) { bstart[t] = 0; bend[t] = 0; }
}

__global__ void bounds_kernel(const int* __restrict__ batch, int* __restrict__ bstart,
                              int* __restrict__ bend, int N) {
    int t = blockIdx.x * blockDim.x + threadIdx.x;
    if (t >= N) return;
    int b = batch[t];
    if (t == 0 || batch[t - 1] != b) bstart[b] = t;
    if (t == N - 1 || batch[t + 1] != b) bend[b] = t + 1;
}

// ---------------- per-layer: fused q,k,v,skip GEMMs (+qdotu) ----------------
// kv packed fp8 e4m3: row = 8 x uint2; quad cq: {4 k-bytes, 4 v-bytes}. 64B/node.
__global__ void qkvs_kernel(
    const float* __restrict__ xs, int ssrc,
    const float* __restrict__ xd, int sdst,
    const float* __restrict__ Wq, const float* __restrict__ bq,
    const float* __restrict__ Wk, const float* __restrict__ bk,
    const float* __restrict__ Wv, const float* __restrict__ bv,
    const float* __restrict__ Ws, const float* __restrict__ bs,
    const float* __restrict__ u,      // nullptr for non-edge layers
    float* __restrict__ qb, uint2* __restrict__ kv8,
    float* __restrict__ sb, float* __restrict__ qdu, int N)
{
    int lane = threadIdx.x & 63;
    int wid  = __builtin_amdgcn_readfirstlane((int)(threadIdx.x >> 6));
    int wpb  = blockDim.x >> 6;
    int gw   = blockIdx.x * wpb + wid;
    int nw   = gridDim.x * wpb;
    int j    = lane & 31;
    bool lower = lane < 32;

    const float* W1 = lower ? Wq : Wk;
    const float* W2 = lower ? Wv : Ws;
    float rw1[32], rw2[32];
    #pragma unroll
    for (int kk = 0; kk < 32; ++kk) {
        rw1[kk] = W1[kk * 32 + j];
        rw2[kk] = W2[kk * 32 + j];
    }
    float bias1 = lower ? bq[j] : bk[j];
    float bias2 = lower ? bv[j] : bs[j];
    float uj = (u != nullptr) ? u[j] : 0.f;

    for (int n = gw; n < N; n += nw) {
        const float* xdr = xd + (size_t)n * sdst;  // wave-uniform -> scalar loads
        const float* xsr = xs + (size_t)n * ssrc;
        float acc1 = bias1, acc2 = bias2;
        #pragma unroll
        for (int kk = 0; kk < 32; ++kk) {
            float xdv = xdr[kk];
            float xsv = xsr[kk];
            float a  = lower ? xdv : xsv;   // q | k input
            float bb = lower ? xsv : xdv;   // v | skip input
            acc1 = fmaf(a,  rw1[kk], acc1);
            acc2 = fmaf(bb, rw2[kk], acc2);
        }
        float kk_ = __shfl(acc1, j + 32);   // k_j from upper half
        float k1 = __shfl_down(kk_, 1), v1 = __shfl_down(acc2, 1);
        float k2 = __shfl_down(kk_, 2), v2 = __shfl_down(acc2, 2);
        float k3 = __shfl_down(kk_, 3), v3 = __shfl_down(acc2, 3);
        if (lower) {
            qb[(size_t)n * 32 + j] = acc1;                  // q
            if ((j & 3) == 0) {
                int pk = __builtin_amdgcn_cvt_pk_fp8_f32(kk_, k1, 0, false);
                pk = __builtin_amdgcn_cvt_pk_fp8_f32(k2, k3, pk, true);
                int pv = __builtin_amdgcn_cvt_pk_fp8_f32(acc2, v1, 0, false);
                pv = __builtin_amdgcn_cvt_pk_fp8_f32(v2, v3, pv, true);
                kv8[(size_t)n * 8 + (j >> 2)] = make_uint2((unsigned)pk, (unsigned)pv);
            }
        } else {
            sb[(size_t)n * 32 + j] = acc2;                  // skip
        }
        if (u != nullptr) {
            float pp = lower ? acc1 * uj : 0.f;
            pp += __shfl_xor(pp, 16);
            pp += __shfl_xor(pp, 8);
            pp += __shfl_xor(pp, 4);
            pp += __shfl_xor(pp, 2);
            pp += __shfl_xor(pp, 1);
            if (lane == 0) qdu[n] = pp * RSQRT32;
        }
    }
}

// ---------------- per-layer: gather aggregation, one node per OCTET -----------
// 8 nodes/wave: octet o (8 lanes) owns node n; lane cq holds channels 4cq..4cq+3.
// Per edge: octet-broadcast adj load, uint2 fp8 row load (8 lanes = full 64B row),
// 3-step intra-octet shfl dot, exp, lane-final den/num accumulate. NO cross-stream
// reduction tree, prologue/epilogue amortized 8x. 2-stream ILP over edges.
template<int HAS_EA>
__global__ __launch_bounds__(256, 8)
void agg_kernel(const int* __restrict__ rp, const void* __restrict__ adjv,
    const float* __restrict__ qb, const uint2* __restrict__ kv8,
    const float* __restrict__ qdu, const float* __restrict__ u,
    const float* __restrict__ skp, float* __restrict__ xout, int N)
{
    int t = threadIdx.x;
    int lane = t & 63;
    int cq = lane & 7;        // channel quad
    int o  = lane >> 3;       // octet = node slot
    int wv = t >> 6;
    int n = (blockIdx.x * 4 + wv) * 8 + o;   // 32 contiguous nodes per block
    if (n >= N) return;       // no barriers below: safe
    float4 qc = ((const float4*)(qb + (size_t)n * 32))[cq];
    float qd = HAS_EA ? qdu[n] : 0.f;
    float4 uc = HAS_EA ? ((const float4*)u)[cq] : make_float4(0.f, 0.f, 0.f, 0.f);
    int beg = rp[n], end = rp[n + 1];
    const int2* adjE = (const int2*)adjv;
    const int*  adjP = (const int*)adjv;
    float den0 = 0.f, den1 = 0.f;
    float4 num0 = make_float4(0.f, 0.f, 0.f, 0.f);
    float4 num1 = make_float4(0.f, 0.f, 0.f, 0.f);
    int i = beg;
    for (; i + 1 < end; i += 2) {
        int s0, s1; float ae0 = 0.f, ae1 = 0.f;
        if (HAS_EA) {
            int2 a0 = adjE[i], a1 = adjE[i + 1];
            s0 = a0.x; s1 = a1.x;
            ae0 = __int_as_float(a0.y); ae1 = __int_as_float(a1.y);
        } else { s0 = adjP[i]; s1 = adjP[i + 1]; }
        uint2 p0 = kv8[(size_t)s0 * 8 + cq];
        uint2 p1 = kv8[(size_t)s1 * 8 + cq];
        fx2 k001 = __builtin_amdgcn_cvt_pk_f32_fp8((int)p0.x, false);
        fx2 k023 = __builtin_amdgcn_cvt_pk_f32_fp8((int)p0.x, true);
        fx2 w001 = __builtin_amdgcn_cvt_pk_f32_fp8((int)p0.y, false);
        fx2 w023 = __builtin_amdgcn_cvt_pk_f32_fp8((int)p0.y, true);
        fx2 k101 = __builtin_amdgcn_cvt_pk_f32_fp8((int)p1.x, false);
        fx2 k123 = __builtin_amdgcn_cvt_pk_f32_fp8((int)p1.x, true);
        fx2 w101 = __builtin_amdgcn_cvt_pk_f32_fp8((int)p1.y, false);
        fx2 w123 = __builtin_amdgcn_cvt_pk_f32_fp8((int)p1.y, true);
        float d0 = fmaf(qc.x, k001[0], fmaf(qc.y, k001[1], fmaf(qc.z, k023[0], qc.w * k023[1])));
        float d1 = fmaf(qc.x, k101[0], fmaf(qc.y, k101[1], fmaf(qc.z, k123[0], qc.w * k123[1])));
        d0 += __shfl_xor(d0, 1);  d1 += __shfl_xor(d1, 1);
        d0 += __shfl_xor(d0, 2);  d1 += __shfl_xor(d1, 2);
        d0 += __shfl_xor(d0, 4);  d1 += __shfl_xor(d1, 4);
        // softmax is shift-invariant; logits O(+-7) so direct exp is safe
        float ex0 = __expf(fmaf(ae0, qd, d0 * RSQRT32));
        float ex1 = __expf(fmaf(ae1, qd, d1 * RSQRT32));
        den0 += ex0;  den1 += ex1;
        num0.x = fmaf(fmaf(ae0, uc.x, w001[0]), ex0, num0.x);
        num0.y = fmaf(fmaf(ae0, uc.y, w001[1]), ex0, num0.y);
        num0.z = fmaf(fmaf(ae0, uc.z, w023[0]), ex0, num0.z);
        num0.w = fmaf(fmaf(ae0, uc.w, w023[1]), ex0, num0.w);
        num1.x = fmaf(fmaf(ae1, uc.x, w101[0]), ex1, num1.x);
        num1.y = fmaf(fmaf(ae1, uc.y, w101[1]), ex1, num1.y);
        num1.z = fmaf(fmaf(ae1, uc.z, w123[0]), ex1, num1.z);
        num1.w = fmaf(fmaf(ae1, uc.w, w123[1]), ex1, num1.w);
    }
    if (i < end) {
        int s0; float ae0 = 0.f;
        if (HAS_EA) { int2 a0 = adjE[i]; s0 = a0.x; ae0 = __int_as_float(a0.y); }
        else s0 = adjP[i];
        uint2 p0 = kv8[(size_t)s0 * 8 + cq];
        fx2 k001 = __builtin_amdgcn_cvt_pk_f32_fp8((int)p0.x, false);
        fx2 k023 = __builtin_amdgcn_cvt_pk_f32_fp8((int)p0.x, true);
        fx2 w001 = __builtin_amdgcn_cvt_pk_f32_fp8((int)p0.y, false);
        fx2 w023 = __builtin_amdgcn_cvt_pk_f32_fp8((int)p0.y, true);
        float d0 = fmaf(qc.x, k001[0], fmaf(qc.y, k001[1], fmaf(qc.z, k023[0], qc.w * k023[1])));
        d0 += __shfl_xor(d0, 1);
        d0 += __shfl_xor(d0, 2);
        d0 += __shfl_xor(d0, 4);
        float ex0 = __expf(fmaf(ae0, qd, d0 * RSQRT32));
        den0 += ex0;
        num0.x = fmaf(fmaf(ae0, uc.x, w001[0]), ex0, num0.x);
        num0.y = fmaf(fmaf(ae0, uc.y, w001[1]), ex0, num0.y);
        num0.z = fmaf(fmaf(ae0, uc.z, w023[0]), ex0, num0.z);
        num0.w = fmaf(fmaf(ae0, uc.w, w023[1]), ex0, num0.w);
    }
    float den = den0 + den1;                 // replicated across the octet
    float inv = 1.f / (den + 1e-16f);
    float4 sk = ((const float4*)(skp + (size_t)n * 32))[cq];
    float4 ov;
    ov.x = tanhf(fmaf(num0.x + num1.x, inv, sk.x));
    ov.y = tanhf(fmaf(num0.y + num1.y, inv, sk.y));
    ov.z = tanhf(fmaf(num0.z + num1.z, inv, sk.z));
    ov.w = tanhf(fmaf(num0.w + num1.w, inv, sk.w));
    ((float4*)(xout + (size_t)n * 32))[cq] = ov;   // 8 lanes = full 128B row
}

// ---------------- per-layer pooling (coalesced; 1 atomic row per block) --------
__global__ void pool_kernel(const float* __restrict__ x,
                            const int* __restrict__ bstart, const int* __restrict__ bend,
                            float* __restrict__ poolsum, int layer_off) {
    __shared__ float red[256];
    int b = blockIdx.x >> 3, sub = blockIdx.x & 7;
    int s0 = bstart[b], s1 = bend[b];
    int cnt = s1 - s0;
    int n0 = s0 + (int)((long long)cnt * sub / 8);
    int n1 = s0 + (int)((long long)cnt * (sub + 1) / 8);
    int t = threadIdx.x, col = t & 31, g = t >> 5;
    float acc = 0.f;
    for (int n = n0 + g; n < n1; n += 8)
        acc += x[(size_t)n * 32 + col];
    red[t] = acc;
    __syncthreads();
    if (t < 32) {
        float s = red[t];
        #pragma unroll
        for (int k = 1; k < 8; ++k) s += red[t + 32 * k];
        atomicAdd(&poolsum[(size_t)b * 288 + layer_off + t], s);
    }
}

// ---------------- head ----------------

__device__ __forceinline__ void gemv_step(const float* __restrict__ W, const float* __restrict__ bias,
    const float* sin_, float* sout, int K, int M, int t, bool do_relu) {
    if (t < M) {
        float acc = bias[t];
        for (int kk = 0; kk < K; ++kk) acc = fmaf(sin_[kk], W[kk * M + t], acc);
        sout[t] = do_relu ? fmaxf(acc, 0.f) : acc;
    }
    __syncthreads();
}

__global__ void head_kernel(const float* __restrict__ poolsum,
    const int* __restrict__ bstart, const int* __restrict__ bend,
    const float* __restrict__ W1, const float* __restrict__ b1,
    const float* __restrict__ W2, const float* __restrict__ b2,
    const float* __restrict__ W3, const float* __restrict__ b3,
    const float* __restrict__ W4, const float* __restrict__ b4,
    const float* __restrict__ W5, const float* __restrict__ b5,
    const float* __restrict__ W6, const float* __restrict__ b6,
    float* __restrict__ out)
{
    __shared__ float ha[288], hb[288];
    __shared__ float lse;
    int b = blockIdx.x, t = threadIdx.x;
    float invc = 1.f / fmaxf((float)(bend[b] - bstart[b]), 1.f);
    if (t < 288) ha[t] = poolsum[(size_t)b * 288 + t] * invc;
    __syncthreads();
    gemv_step(W1, b1, ha, hb, 288, 288, t, false);
    gemv_step(W2, b2, hb, ha, 288, 144, t, true);
    gemv_step(W3, b3, ha, hb, 144, 144, t, false);
    gemv_step(W4, b4, hb, ha, 144, 72,  t, false);
    gemv_step(W5, b5, ha, hb, 72,  72,  t, false);
    gemv_step(W6, b6, hb, ha, 72,  10,  t, false);
    if (t == 0) {
        float m = ha[0];
        for (int i = 1; i < 10; ++i) m = fmaxf(m, ha[i]);
        float ssum = 0.f;
        for (int i = 0; i < 10; ++i) ssum += __expf(ha[i] - m);
        lse = m + logf(ssum);
    }
    __syncthreads();
    if (t < 10) out[b * 10 + t] = ha[t] - lse;
}

// ---------------- launch ----------------

extern "C" void kernel_launch(void* const* d_in, const int* in_sizes, int n_in,
                              void* d_out, int out_size, void* d_ws, size_t ws_size,
                              hipStream_t stream)
{
    const float* inter_emb = (const float*)d_in[0];
    const float* edge_attr = (const float*)d_in[1];
    const float* uv_emb    = (const float*)d_in[2];
    const int* inter_idx = (const int*)d_in[3];
    const int* uvt_idx   = (const int*)d_in[4];
    const int* tuv_idx   = (const int*)d_in[5];
    const int* batch     = (const int*)d_in[6];
    const float* cWq = (const float*)d_in[7];  const float* cbq = (const float*)d_in[8];
    const float* cWk = (const float*)d_in[9];  const float* cbk = (const float*)d_in[10];
    const float* cWv = (const float*)d_in[11]; const float* cbv = (const float*)d_in[12];
    const float* cWs = (const float*)d_in[13]; const float* cbs = (const float*)d_in[14];
    const float* cWe = (const float*)d_in[15];
    const float* W1 = (const float*)d_in[16]; const float* b1 = (const float*)d_in[17];
    const float* W2 = (const float*)d_in[18]; const float* b2 = (const float*)d_in[19];
    const float* W3 = (const float*)d_in[20]; const float* b3 = (const float*)d_in[21];
    const float* W4 = (const float*)d_in[22]; const float* b4 = (const float*)d_in[23];
    const float* W5 = (const float*)d_in[24]; const float* b5 = (const float*)d_in[25];
    const float* W6 = (const float*)d_in[26]; const float* b6 = (const float*)d_in[27];

    const int N = in_sizes[2] / 32;
    const int E = in_sizes[1];
    const int B = out_size / 10;
    const int G = (N + TILE - 1) / TILE;
    const int BS = (N + NS - 1) / NS;      // bins per slice (<= MAXBS)
    const int CH = (E + NC - 1) / NC;      // edges per chunk

    char* p = (char*)d_ws;
    auto alloc = [&](size_t bytes) { char* r = p; p += (bytes + 255) & ~(size_t)255; return r; };
    float*   qb    = (float*)alloc((size_t)N * 32 * 4);
    uint2*   kv8   = (uint2*)alloc((size_t)N * 64);     // fp8 {k[4],v[4]} per quad
    float*   sb    = (float*)alloc((size_t)N * 32 * 4);
    float*   qdu   = (float*)alloc((size_t)N * 4);
    float*   xa    = (float*)alloc((size_t)N * 32 * 4);
    float*   xb    = (float*)alloc((size_t)N * 32 * 4);
    float*   ub    = (float*)alloc(96 * 4);
    float*   poolsum = (float*)alloc((size_t)B * 288 * 4);
    int*     bstart = (int*)alloc((size_t)B * 4);
    int*     bend   = (int*)alloc((size_t)B * 4);
    int*     cnt3  = (int*)alloc((size_t)3 * N * 4);
    int*     rp3   = (int*)alloc((size_t)3 * (N + 1) * 4);
    int*     tsum  = (int*)alloc((size_t)3 * G * 4);
    unsigned short* partial = (unsigned short*)alloc((size_t)3 * NS * NC * BS * 2);
    int2*    adj0  = (int2*)alloc((size_t)E * 8);
    int*     adj12 = (int*)alloc((size_t)2 * E * 4);

    // ---- CSR build: counting sort, no global atomics ----
    hist_lds<<<3 * NS * NC, 256, 0, stream>>>(inter_idx, uvt_idx, tuv_idx, E, N, BS, CH, partial);
    chunk_scan<<<(3 * NS * BS + 255) / 256, 256, 0, stream>>>(partial, cnt3, N, BS);
    scan_tiles_sum<<<3 * G, 256, 0, stream>>>(cnt3, tsum, N, G);
    scan_offsets<<<1, 64, 0, stream>>>(tsum, rp3, N, G);
    scan_write<<<3 * G, 256, 0, stream>>>(cnt3, tsum, rp3, N, G);
    scatter_cs<<<3 * NS * NC, 256, 0, stream>>>(inter_idx, uvt_idx, tuv_idx, edge_attr,
                                                partial, rp3, adj0, adj12, E, N, BS, CH);

    hipMemsetAsync(poolsum, 0, (size_t)B * 288 * 4, stream);
    colsum_kernel<<<1, 128, 0, stream>>>(cWe, ub, bstart, bend, B);
    bounds_kernel<<<(N + 255) / 256, 256, 0, stream>>>(batch, bstart, bend, N);

    float* xcur = nullptr;
    float* xnext = xa;
    for (int i = 0; i < 9; ++i) {
        int r = i % 3;
        const float* xsrc; int ssrc; const float* xdst; int sdst;
        if (i == 0)      { xsrc = inter_emb; ssrc = 64; xdst = inter_emb + 32; sdst = 64; }
        else if (r == 0) { xsrc = xcur; ssrc = 32; xdst = xcur;  sdst = 32; }
        else if (r == 1) { xsrc = xcur; ssrc = 32; xdst = uv_emb; sdst = 32; }
        else             { xsrc = uv_emb; ssrc = 32; xdst = xcur; sdst = 32; }
        const float* ul = (r == 0) ? (ub + (i / 3) * 32) : nullptr;

        qkvs_kernel<<<1024, 256, 0, stream>>>(xsrc, ssrc, xdst, sdst,
            cWq + i * 1024, cbq + i * 32, cWk + i * 1024, cbk + i * 32,
            cWv + i * 1024, cbv + i * 32, cWs + i * 1024, cbs + i * 32,
            ul, qb, kv8, sb, qdu, N);
        const int* rpl = rp3 + (size_t)r * (N + 1);
        if (r == 0) {
            agg_kernel<1><<<(N + 31) / 32, 256, 0, stream>>>(
                rpl, adj0, qb, kv8, qdu, ul, sb, xnext, N);
        } else {
            agg_kernel<0><<<(N + 31) / 32, 256, 0, stream>>>(
                rpl, adj12 + (size_t)(r - 1) * E, qb, kv8, qdu, ul, sb, xnext, N);
        }
        pool_kernel<<<B * 8, 256, 0, stream>>>(xnext, bstart, bend, poolsum, i * 32);
        xcur = xnext;
        xnext = (xnext == xa) ? xb : xa;
    }

    head_kernel<<<B, 320, 0, stream>>>(poolsum, bstart, bend,
        W1, b1, W2, b2, W3, b3, W4, b4, W5, b5, W6, b6, (float*)d_out);
}